// Round 2
// baseline (156.847 us; speedup 1.0000x reference)
//
#include <hip/hip_runtime.h>

#define BB 4
#define TT 64
#define SS 256
#define DD 512
#define FEMB 128

__device__ __forceinline__ float fast_tanh(float x) {
    x = fminf(fmaxf(x, -10.f), 10.f);
    float t = __expf(2.f * x);
    return (t - 1.f) / (t + 1.f);
}

// Fused 4-GEMM + bias + tanh.  C = tanh(A @ W^T + b), A:[M,K] row-major, W:[512,K] row-major.
// Packed 1D grid of 320 active 64x64 tiles:
//   [0,128)   H  = tanh(X @ W1^T + b1)   M=1024 K=512  (16y x 8x)
//   [128,256) Fo = tanh(Z @ W3^T + b3)   M=1024 K=128
//   [256,288) O2 = tanh(Y @ W2^T + b2)   M=256  K=512  (4y x 8x)
//   [288,320) O3 = tanh(Y @ W4^T + b4)   M=256  K=512
__global__ __launch_bounds__(256) void gemm_tanh_kernel(
    const float* __restrict__ X, const float* __restrict__ Z, const float* __restrict__ Y,
    const float* __restrict__ W1, const float* __restrict__ b1,
    const float* __restrict__ W2, const float* __restrict__ b2,
    const float* __restrict__ W3, const float* __restrict__ b3,
    const float* __restrict__ W4, const float* __restrict__ b4,
    float* __restrict__ H, float* __restrict__ Fo,
    float* __restrict__ O2, float* __restrict__ O3)
{
    int id = blockIdx.x;
    const float* A; const float* W; const float* bias; float* C; int K;
    if (id < 128)      { A = X; W = W1; bias = b1; C = H;  K = 512; }
    else if (id < 256) { id -= 128; A = Z; W = W3; bias = b3; C = Fo; K = 128; }
    else if (id < 288) { id -= 256; A = Y; W = W2; bias = b2; C = O2; K = 512; }
    else               { id -= 288; A = Y; W = W4; bias = b4; C = O3; K = 512; }
    const int m0 = (id >> 3) * 64;
    const int n0 = (id & 7) * 64;

    __shared__ float As[16][68];
    __shared__ float Ws[16][68];

    const int tid  = threadIdx.x;
    const int lrow = tid >> 2;   // 0..63
    const int lkv  = tid & 3;    // 0..3
    const int ty   = tid >> 4;   // 0..15
    const int tx   = tid & 15;   // 0..15

    float acc[4][4] = {};

    // register prefetch double-buffer: load k0=0 now; inside the loop, issue
    // the k0+16 load right after the barrier so its latency overlaps the
    // 16-step FMA burst (consumed at next iteration's LDS store).
    const float* Ap = &A[(m0 + lrow) * K + lkv * 4];
    const float* Wp = &W[(n0 + lrow) * K + lkv * 4];
    float4 av = *(const float4*)Ap;
    float4 wv = *(const float4*)Wp;

    for (int k0 = 0; k0 < K; k0 += 16) {
        __syncthreads();   // prev iter's LDS reads complete
        As[lkv*4+0][lrow] = av.x; As[lkv*4+1][lrow] = av.y;
        As[lkv*4+2][lrow] = av.z; As[lkv*4+3][lrow] = av.w;
        Ws[lkv*4+0][lrow] = wv.x; Ws[lkv*4+1][lrow] = wv.y;
        Ws[lkv*4+2][lrow] = wv.z; Ws[lkv*4+3][lrow] = wv.w;
        __syncthreads();
        if (k0 + 16 < K) {
            av = *(const float4*)(Ap + k0 + 16);
            wv = *(const float4*)(Wp + k0 + 16);
        }
        #pragma unroll
        for (int k = 0; k < 16; ++k) {
            float4 a4 = *(const float4*)&As[k][ty * 4];
            float4 w4 = *(const float4*)&Ws[k][tx * 4];
            float a[4] = {a4.x, a4.y, a4.z, a4.w};
            float w[4] = {w4.x, w4.y, w4.z, w4.w};
            #pragma unroll
            for (int i = 0; i < 4; ++i)
                #pragma unroll
                for (int j = 0; j < 4; ++j)
                    acc[i][j] = fmaf(a[i], w[j], acc[i][j]);
        }
    }

    float4 bb = *(const float4*)&bias[n0 + tx * 4];
    float bj[4] = {bb.x, bb.y, bb.z, bb.w};
    #pragma unroll
    for (int i = 0; i < 4; ++i) {
        const int m = m0 + ty * 4 + i;
        float4 o;
        o.x = fast_tanh(acc[i][0] + bj[0]);
        o.y = fast_tanh(acc[i][1] + bj[1]);
        o.z = fast_tanh(acc[i][2] + bj[2]);
        o.w = fast_tanh(acc[i][3] + bj[3]);
        *(float4*)&C[m * DD + n0 + tx * 4] = o;
    }
}

// Attention: attn[b,t,d] = sum_s softmax_s(H*u + F*v) * enc.  |w|<=2, no max needed.
// 256 blocks x 256 threads; threads split the s-range 2-way (sh=tid>>7), each
// half runs 128 s-steps, then l/acc combine through padded LDS.
__global__ __launch_bounds__(256) void attn_kernel(
    const float* __restrict__ H, const float* __restrict__ Fo,
    const float* __restrict__ X,   // enc, [1024,512] flat
    const float* __restrict__ O2, const float* __restrict__ O3,
    const float* __restrict__ Y,   // [256,512] flat
    float* __restrict__ out)
{
    const int idx = blockIdx.x;                    // 0..255
    const int b   = (idx & 7) >> 1;                // XCD-pair per batch
    const int rem = ((idx >> 3) << 1) | (idx & 1); // 0..63
    const int t0  = (rem >> 2) * 4;
    const int dq  = rem & 3;
    const int tid = threadIdx.x;
    const int dl  = tid & 127;
    const int d   = dq * 128 + dl;
    const int sh  = tid >> 7;                      // s-half 0/1

    float u[4], v[4];
    #pragma unroll
    for (int j = 0; j < 4; ++j) {
        const int bt = b * TT + t0 + j;
        u[j] = O2[bt * DD + d];
        v[j] = O3[bt * DD + d];
    }

    float l[4]   = {0.f, 0.f, 0.f, 0.f};
    float acc[4] = {0.f, 0.f, 0.f, 0.f};
    const int base = (b * SS + sh * 128) * DD + d;
    const float* Hb = H  + base;
    const float* Fb = Fo + base;
    const float* Eb = X  + base;

    #pragma unroll 8
    for (int s = 0; s < 128; ++s) {
        const float h = Hb[s * DD];
        const float f = Fb[s * DD];
        const float e = Eb[s * DD];
        #pragma unroll
        for (int j = 0; j < 4; ++j) {
            const float w  = fmaf(h, u[j], f * v[j]);
            const float ex = __expf(w);
            l[j]  += ex;
            acc[j] = fmaf(ex, e, acc[j]);
        }
    }

    __shared__ float red[128][9];  // +1 pad breaks the 8-stride bank pattern
    if (sh == 1) {
        #pragma unroll
        for (int j = 0; j < 4; ++j) { red[dl][j] = l[j]; red[dl][4 + j] = acc[j]; }
    }
    __syncthreads();
    if (sh == 0) {
        #pragma unroll
        for (int j = 0; j < 4; ++j) {
            const float lt = l[j] + red[dl][j];
            const float at = acc[j] + red[dl][4 + j];
            const int bt = b * TT + t0 + j;
            const float a = at / lt;
            out[BB * TT * 2 * DD + bt * DD + d] = a;        // attn (output 1)
            out[bt * 2 * DD + DD + d]           = a;        // concat second half
            out[bt * 2 * DD + d]                = Y[bt * DD + d]; // concat first half
        }
    }
}

extern "C" void kernel_launch(void* const* d_in, const int* in_sizes, int n_in,
                              void* d_out, int out_size, void* d_ws, size_t ws_size,
                              hipStream_t stream)
{
    const float* Y  = (const float*)d_in[0];   // output          [4,64,512]
    const float* X  = (const float*)d_in[1];   // encoder_hidden  [1024,512] flat
    const float* Z  = (const float*)d_in[2];   // input_z         [1024,128] flat
    const float* W1 = (const float*)d_in[3];
    const float* b1 = (const float*)d_in[4];
    const float* W2 = (const float*)d_in[5];
    const float* b2 = (const float*)d_in[6];
    const float* W3 = (const float*)d_in[7];
    const float* b3 = (const float*)d_in[8];
    const float* W4 = (const float*)d_in[9];
    const float* b4 = (const float*)d_in[10];
    float* out = (float*)d_out;

    float* H  = (float*)d_ws;
    float* Fo = H  + 1024 * 512;
    float* O2 = Fo + 1024 * 512;
    float* O3 = O2 + 256 * 512;

    gemm_tanh_kernel<<<320, 256, 0, stream>>>(X, Z, Y, W1, b1, W2, b2, W3, b3, W4, b4,
                                              H, Fo, O2, O3);
    attn_kernel<<<256, 256, 0, stream>>>(H, Fo, X, O2, O3, Y, out);
}

// Round 3
// 118.078 us; speedup vs baseline: 1.3283x; 1.3283x over previous
//
#include <hip/hip_runtime.h>

#define BB 4
#define TT 64
#define SS 256
#define DD 512
#define FEMB 128

__device__ __forceinline__ float fast_tanh(float x) {
    x = fminf(fmaxf(x, -10.f), 10.f);
    float t = __expf(2.f * x);
    return (t - 1.f) / (t + 1.f);
}

// Fused 4-GEMM + bias + tanh.  C = tanh(A @ W^T + b), A:[M,K] row-major, W:[512,K] row-major.
// Packed 1D grid of 320 active 64x64 tiles.
__global__ __launch_bounds__(256) void gemm_tanh_kernel(
    const float* __restrict__ X, const float* __restrict__ Z, const float* __restrict__ Y,
    const float* __restrict__ W1, const float* __restrict__ b1,
    const float* __restrict__ W2, const float* __restrict__ b2,
    const float* __restrict__ W3, const float* __restrict__ b3,
    const float* __restrict__ W4, const float* __restrict__ b4,
    float* __restrict__ H, float* __restrict__ Fo,
    float* __restrict__ O2, float* __restrict__ O3)
{
    int id = blockIdx.x;
    const float* A; const float* W; const float* bias; float* C; int K;
    if (id < 128)      { A = X; W = W1; bias = b1; C = H;  K = 512; }
    else if (id < 256) { id -= 128; A = Z; W = W3; bias = b3; C = Fo; K = 128; }
    else if (id < 288) { id -= 256; A = Y; W = W2; bias = b2; C = O2; K = 512; }
    else               { id -= 288; A = Y; W = W4; bias = b4; C = O3; K = 512; }
    const int m0 = (id >> 3) * 64;
    const int n0 = (id & 7) * 64;

    __shared__ float As[16][68];
    __shared__ float Ws[16][68];

    const int tid  = threadIdx.x;
    const int lrow = tid >> 2;   // 0..63
    const int lkv  = tid & 3;    // 0..3
    const int ty   = tid >> 4;   // 0..15
    const int tx   = tid & 15;   // 0..15

    float acc[4][4] = {};

    const float* Ap = &A[(m0 + lrow) * K + lkv * 4];
    const float* Wp = &W[(n0 + lrow) * K + lkv * 4];
    float4 av = *(const float4*)Ap;
    float4 wv = *(const float4*)Wp;

    for (int k0 = 0; k0 < K; k0 += 16) {
        __syncthreads();
        As[lkv*4+0][lrow] = av.x; As[lkv*4+1][lrow] = av.y;
        As[lkv*4+2][lrow] = av.z; As[lkv*4+3][lrow] = av.w;
        Ws[lkv*4+0][lrow] = wv.x; Ws[lkv*4+1][lrow] = wv.y;
        Ws[lkv*4+2][lrow] = wv.z; Ws[lkv*4+3][lrow] = wv.w;
        __syncthreads();
        if (k0 + 16 < K) {
            av = *(const float4*)(Ap + k0 + 16);
            wv = *(const float4*)(Wp + k0 + 16);
        }
        #pragma unroll
        for (int k = 0; k < 16; ++k) {
            float4 a4 = *(const float4*)&As[k][ty * 4];
            float4 w4 = *(const float4*)&Ws[k][tx * 4];
            float a[4] = {a4.x, a4.y, a4.z, a4.w};
            float w[4] = {w4.x, w4.y, w4.z, w4.w};
            #pragma unroll
            for (int i = 0; i < 4; ++i)
                #pragma unroll
                for (int j = 0; j < 4; ++j)
                    acc[i][j] = fmaf(a[i], w[j], acc[i][j]);
        }
    }

    float4 bb = *(const float4*)&bias[n0 + tx * 4];
    float bj[4] = {bb.x, bb.y, bb.z, bb.w};
    #pragma unroll
    for (int i = 0; i < 4; ++i) {
        const int m = m0 + ty * 4 + i;
        float4 o;
        o.x = fast_tanh(acc[i][0] + bj[0]);
        o.y = fast_tanh(acc[i][1] + bj[1]);
        o.z = fast_tanh(acc[i][2] + bj[2]);
        o.w = fast_tanh(acc[i][3] + bj[3]);
        *(float4*)&C[m * DD + n0 + tx * 4] = o;
    }
}

// Attention: attn[b,t,d] = sum_s softmax_s(H*u + F*v) * enc.  |w|<=2, no max needed.
// 512 blocks x 512 threads: (b, t-pair, d-quarter) x 4-way in-block s-split.
// Explicit 8-deep load arrays force ~24 outstanding L2 loads per thread.
__global__ __launch_bounds__(512) void attn_kernel(
    const float* __restrict__ H, const float* __restrict__ Fo,
    const float* __restrict__ X,   // enc, [1024,512] flat
    const float* __restrict__ O2, const float* __restrict__ O3,
    const float* __restrict__ Y,   // [256,512] flat
    float* __restrict__ out)
{
    const int idx = blockIdx.x;                    // 0..511
    const int b   = (idx & 7) >> 1;                // XCD-pair per batch: 6MB slice fits 2x4MB L2
    const int rem = ((idx >> 3) << 1) | (idx & 1); // 0..127
    const int t0  = (rem >> 2) * 2;                // t-pair
    const int dq  = rem & 3;
    const int tid = threadIdx.x;
    const int dl  = tid & 127;
    const int d   = dq * 128 + dl;
    const int sq  = tid >> 7;                      // s-quarter 0..3

    const int bt0 = b * TT + t0;
    const float u0 = O2[bt0 * DD + d],       v0 = O3[bt0 * DD + d];
    const float u1 = O2[(bt0 + 1) * DD + d], v1 = O3[(bt0 + 1) * DD + d];

    float l0 = 0.f, l1 = 0.f, a0 = 0.f, a1 = 0.f;
    const int base = (b * SS + sq * 64) * DD + d;
    const float* Hb = H  + base;
    const float* Fb = Fo + base;
    const float* Eb = X  + base;

    for (int s0 = 0; s0 < 64; s0 += 8) {
        float h[8], f[8], e[8];
        #pragma unroll
        for (int s = 0; s < 8; ++s) h[s] = Hb[(s0 + s) * DD];
        #pragma unroll
        for (int s = 0; s < 8; ++s) f[s] = Fb[(s0 + s) * DD];
        #pragma unroll
        for (int s = 0; s < 8; ++s) e[s] = Eb[(s0 + s) * DD];
        #pragma unroll
        for (int s = 0; s < 8; ++s) {
            const float w0 = fmaf(h[s], u0, f[s] * v0);
            const float x0 = __expf(w0);
            l0 += x0; a0 = fmaf(x0, e[s], a0);
            const float w1 = fmaf(h[s], u1, f[s] * v1);
            const float x1 = __expf(w1);
            l1 += x1; a1 = fmaf(x1, e[s], a1);
        }
    }

    __shared__ float red[3][128][9];  // stride 9: conflict-free
    if (sq) {
        red[sq-1][dl][0] = l0; red[sq-1][dl][1] = l1;
        red[sq-1][dl][2] = a0; red[sq-1][dl][3] = a1;
    }
    __syncthreads();
    if (sq == 0) {
        #pragma unroll
        for (int q = 0; q < 3; ++q) {
            l0 += red[q][dl][0]; l1 += red[q][dl][1];
            a0 += red[q][dl][2]; a1 += red[q][dl][3];
        }
        const float r0 = a0 / l0, r1 = a1 / l1;
        out[BB * TT * 2 * DD + bt0 * DD + d]       = r0;
        out[BB * TT * 2 * DD + (bt0 + 1) * DD + d] = r1;
        out[bt0 * 2 * DD + DD + d]                 = r0;
        out[(bt0 + 1) * 2 * DD + DD + d]           = r1;
        out[bt0 * 2 * DD + d]                      = Y[bt0 * DD + d];
        out[(bt0 + 1) * 2 * DD + d]                = Y[(bt0 + 1) * DD + d];
    }
}

extern "C" void kernel_launch(void* const* d_in, const int* in_sizes, int n_in,
                              void* d_out, int out_size, void* d_ws, size_t ws_size,
                              hipStream_t stream)
{
    const float* Y  = (const float*)d_in[0];
    const float* X  = (const float*)d_in[1];
    const float* Z  = (const float*)d_in[2];
    const float* W1 = (const float*)d_in[3];
    const float* b1 = (const float*)d_in[4];
    const float* W2 = (const float*)d_in[5];
    const float* b2 = (const float*)d_in[6];
    const float* W3 = (const float*)d_in[7];
    const float* b3 = (const float*)d_in[8];
    const float* W4 = (const float*)d_in[9];
    const float* b4 = (const float*)d_in[10];
    float* out = (float*)d_out;

    float* H  = (float*)d_ws;
    float* Fo = H  + 1024 * 512;
    float* O2 = Fo + 1024 * 512;
    float* O3 = O2 + 256 * 512;

    gemm_tanh_kernel<<<320, 256, 0, stream>>>(X, Z, Y, W1, b1, W2, b2, W3, b3, W4, b4,
                                              H, Fo, O2, O3);
    attn_kernel<<<512, 512, 0, stream>>>(H, Fo, X, O2, O3, Y, out);
}

// Round 4
// 111.909 us; speedup vs baseline: 1.4016x; 1.0551x over previous
//
#include <hip/hip_runtime.h>

#define BB 4
#define TT 64
#define SS 256
#define DD 512
#define FEMB 128

typedef __attribute__((ext_vector_type(8))) short short8;    // 8 bf16 = 4 VGPRs
typedef __attribute__((ext_vector_type(4))) float floatx4;

__device__ __forceinline__ float fast_tanh(float x) {
    x = fminf(fmaxf(x, -10.f), 10.f);
    float t = __expf(2.f * x);
    return (t - 1.f) / (t + 1.f);
}

// RNE-pack two fp32 into a uint of two bf16 (lo, hi)
__device__ __forceinline__ unsigned int pack_bf2(float a, float b) {
    union { float f; unsigned int u; } ca, cb;
    ca.f = a; cb.f = b;
    unsigned int ua = ca.u + 0x7FFF + ((ca.u >> 16) & 1);
    unsigned int ub = cb.u + 0x7FFF + ((cb.u >> 16) & 1);
    return (ua >> 16) | (ub & 0xFFFF0000u);
}

// ---- fp32 -> bf16 pre-convert: X, Z, Y, W1, W2, W3, W4 (1.64M elems, float4 in / uint2 out)
__global__ __launch_bounds__(256) void cvt_kernel(
    const float* __restrict__ X, const float* __restrict__ Z, const float* __restrict__ Y,
    const float* __restrict__ W1, const float* __restrict__ W2,
    const float* __restrict__ W3, const float* __restrict__ W4,
    unsigned short* __restrict__ Xb, unsigned short* __restrict__ Zb,
    unsigned short* __restrict__ Yb, unsigned short* __restrict__ W1b,
    unsigned short* __restrict__ W2b, unsigned short* __restrict__ W3b,
    unsigned short* __restrict__ W4b)
{
    const int e = (blockIdx.x * 256 + threadIdx.x) * 4;
    const float* src; unsigned short* dst; int off;
    if (e < 524288)       { src = X;  dst = Xb;  off = 0; }
    else if (e < 655360)  { src = Z;  dst = Zb;  off = 524288; }
    else if (e < 786432)  { src = Y;  dst = Yb;  off = 655360; }
    else if (e < 1048576) { src = W1; dst = W1b; off = 786432; }
    else if (e < 1310720) { src = W2; dst = W2b; off = 1048576; }
    else if (e < 1376256) { src = W3; dst = W3b; off = 1310720; }
    else                  { src = W4; dst = W4b; off = 1376256; }
    const int i = e - off;
    float4 v = *(const float4*)&src[i];
    uint2 p;
    p.x = pack_bf2(v.x, v.y);
    p.y = pack_bf2(v.z, v.w);
    *(uint2*)&dst[i] = p;
}

// ---- bf16 MFMA GEMM+tanh: C = tanh(A @ W^T + b).  A:[M,K], W:[512,K] row-major bf16.
// Packed 320 blocks of 64x64 tiles; 4 waves/block, wave = 16 rows x 64 cols
// (4x mfma_f32_16x16x32_bf16).  Fragments loaded straight from global (L2-resident),
// 1-iter register prefetch, no LDS, no barriers.
__global__ __launch_bounds__(256) void gemm_mfma_kernel(
    const unsigned short* __restrict__ Xb, const unsigned short* __restrict__ Zb,
    const unsigned short* __restrict__ Yb,
    const unsigned short* __restrict__ W1b, const unsigned short* __restrict__ W2b,
    const unsigned short* __restrict__ W3b, const unsigned short* __restrict__ W4b,
    const float* __restrict__ b1, const float* __restrict__ b2,
    const float* __restrict__ b3, const float* __restrict__ b4,
    float* __restrict__ H, float* __restrict__ Fo,
    float* __restrict__ O2, float* __restrict__ O3)
{
    int id = blockIdx.x;
    const unsigned short* A; const unsigned short* W; const float* bias; float* C; int K;
    if (id < 128)      { A = Xb; W = W1b; bias = b1; C = H;  K = 512; }
    else if (id < 256) { id -= 128; A = Zb; W = W3b; bias = b3; C = Fo; K = 128; }
    else if (id < 288) { id -= 256; A = Yb; W = W2b; bias = b2; C = O2; K = 512; }
    else               { id -= 288; A = Yb; W = W4b; bias = b4; C = O3; K = 512; }
    const int m0 = (id >> 3) * 64;
    const int n0 = (id & 7) * 64;
    const int wv   = threadIdx.x >> 6;   // wave 0..3 -> 16-row stripe
    const int lane = threadIdx.x & 63;
    const int fr   = lane & 15;          // fragment row (A) / col (B)
    const int kh   = (lane >> 4) * 8;    // k sub-offset

    const unsigned short* Ap = A + (m0 + wv * 16 + fr) * K + kh;
    const unsigned short* Wp = W + (n0 + fr) * K + kh;
    const int WS = 16 * K;               // n-tile stride in W

    floatx4 acc0 = {0.f,0.f,0.f,0.f}, acc1 = acc0, acc2 = acc0, acc3 = acc0;

    short8 a  = *(const short8*)Ap;
    short8 w0 = *(const short8*)(Wp);
    short8 w1 = *(const short8*)(Wp + WS);
    short8 w2 = *(const short8*)(Wp + 2 * WS);
    short8 w3 = *(const short8*)(Wp + 3 * WS);

    for (int k0 = 0; k0 < K; k0 += 32) {
        const int kn = (k0 + 32 < K) ? (k0 + 32) : 0;   // wrap: dummy (valid) prefetch on last iter
        short8 an  = *(const short8*)(Ap + kn);
        short8 wn0 = *(const short8*)(Wp + kn);
        short8 wn1 = *(const short8*)(Wp + WS + kn);
        short8 wn2 = *(const short8*)(Wp + 2 * WS + kn);
        short8 wn3 = *(const short8*)(Wp + 3 * WS + kn);
        acc0 = __builtin_amdgcn_mfma_f32_16x16x32_bf16(a, w0, acc0, 0, 0, 0);
        acc1 = __builtin_amdgcn_mfma_f32_16x16x32_bf16(a, w1, acc1, 0, 0, 0);
        acc2 = __builtin_amdgcn_mfma_f32_16x16x32_bf16(a, w2, acc2, 0, 0, 0);
        acc3 = __builtin_amdgcn_mfma_f32_16x16x32_bf16(a, w3, acc3, 0, 0, 0);
        a = an; w0 = wn0; w1 = wn1; w2 = wn2; w3 = wn3;
    }

    // C/D layout: col = lane&15, row = (lane>>4)*4 + reg   [m89-verified]
    const int orow  = m0 + wv * 16 + (lane >> 4) * 4;
    const int ocol0 = n0 + fr;
    const float bv0 = bias[ocol0], bv1 = bias[ocol0 + 16],
                bv2 = bias[ocol0 + 32], bv3 = bias[ocol0 + 48];
    #pragma unroll
    for (int r = 0; r < 4; ++r) {
        float* Cr = C + (orow + r) * DD + ocol0;
        Cr[0]  = fast_tanh(acc0[r] + bv0);
        Cr[16] = fast_tanh(acc1[r] + bv1);
        Cr[32] = fast_tanh(acc2[r] + bv2);
        Cr[48] = fast_tanh(acc3[r] + bv3);
    }
}

// ---- Attention: attn[b,t,d] = sum_s softmax_s(H*u + F*v) * enc.  |w|<=2, no max needed.
__global__ __launch_bounds__(512) void attn_kernel(
    const float* __restrict__ H, const float* __restrict__ Fo,
    const float* __restrict__ X,   // enc, [1024,512] flat
    const float* __restrict__ O2, const float* __restrict__ O3,
    const float* __restrict__ Y,   // [256,512] flat
    float* __restrict__ out)
{
    const int idx = blockIdx.x;                    // 0..511
    const int b   = (idx & 7) >> 1;                // XCD-pair per batch
    const int rem = ((idx >> 3) << 1) | (idx & 1); // 0..127
    const int t0  = (rem >> 2) * 2;                // t-pair
    const int dq  = rem & 3;
    const int tid = threadIdx.x;
    const int dl  = tid & 127;
    const int d   = dq * 128 + dl;
    const int sq  = tid >> 7;                      // s-quarter 0..3

    const int bt0 = b * TT + t0;
    const float u0 = O2[bt0 * DD + d],       v0 = O3[bt0 * DD + d];
    const float u1 = O2[(bt0 + 1) * DD + d], v1 = O3[(bt0 + 1) * DD + d];

    float l0 = 0.f, l1 = 0.f, a0 = 0.f, a1 = 0.f;
    const int base = (b * SS + sq * 64) * DD + d;
    const float* Hb = H  + base;
    const float* Fb = Fo + base;
    const float* Eb = X  + base;

    for (int s0 = 0; s0 < 64; s0 += 8) {
        float h[8], f[8], e[8];
        #pragma unroll
        for (int s = 0; s < 8; ++s) h[s] = Hb[(s0 + s) * DD];
        #pragma unroll
        for (int s = 0; s < 8; ++s) f[s] = Fb[(s0 + s) * DD];
        #pragma unroll
        for (int s = 0; s < 8; ++s) e[s] = Eb[(s0 + s) * DD];
        #pragma unroll
        for (int s = 0; s < 8; ++s) {
            const float w0 = fmaf(h[s], u0, f[s] * v0);
            const float x0 = __expf(w0);
            l0 += x0; a0 = fmaf(x0, e[s], a0);
            const float w1 = fmaf(h[s], u1, f[s] * v1);
            const float x1 = __expf(w1);
            l1 += x1; a1 = fmaf(x1, e[s], a1);
        }
    }

    __shared__ float red[3][128][9];
    if (sq) {
        red[sq-1][dl][0] = l0; red[sq-1][dl][1] = l1;
        red[sq-1][dl][2] = a0; red[sq-1][dl][3] = a1;
    }
    __syncthreads();
    if (sq == 0) {
        #pragma unroll
        for (int q = 0; q < 3; ++q) {
            l0 += red[q][dl][0]; l1 += red[q][dl][1];
            a0 += red[q][dl][2]; a1 += red[q][dl][3];
        }
        const float r0 = a0 / l0, r1 = a1 / l1;
        out[BB * TT * 2 * DD + bt0 * DD + d]       = r0;
        out[BB * TT * 2 * DD + (bt0 + 1) * DD + d] = r1;
        out[bt0 * 2 * DD + DD + d]                 = r0;
        out[(bt0 + 1) * 2 * DD + DD + d]           = r1;
        out[bt0 * 2 * DD + d]                      = Y[bt0 * DD + d];
        out[(bt0 + 1) * 2 * DD + d]                = Y[(bt0 + 1) * DD + d];
    }
}

extern "C" void kernel_launch(void* const* d_in, const int* in_sizes, int n_in,
                              void* d_out, int out_size, void* d_ws, size_t ws_size,
                              hipStream_t stream)
{
    const float* Y  = (const float*)d_in[0];   // output          [4,64,512]
    const float* X  = (const float*)d_in[1];   // encoder_hidden  [1024,512] flat
    const float* Z  = (const float*)d_in[2];   // input_z         [1024,128] flat
    const float* W1 = (const float*)d_in[3];
    const float* b1 = (const float*)d_in[4];
    const float* W2 = (const float*)d_in[5];
    const float* b2 = (const float*)d_in[6];
    const float* W3 = (const float*)d_in[7];
    const float* b3 = (const float*)d_in[8];
    const float* W4 = (const float*)d_in[9];
    const float* b4 = (const float*)d_in[10];
    float* out = (float*)d_out;

    float* H  = (float*)d_ws;            // [1024,512] fp32
    float* Fo = H  + 1024 * 512;         // [1024,512] fp32
    float* O2 = Fo + 1024 * 512;         // [256,512]  fp32
    float* O3 = O2 + 256 * 512;          // [256,512]  fp32
    unsigned short* Xb  = (unsigned short*)(O3 + 256 * 512);  // bf16 region (16B-aligned)
    unsigned short* Zb  = Xb  + 524288;
    unsigned short* Yb  = Zb  + 131072;
    unsigned short* W1b = Yb  + 131072;
    unsigned short* W2b = W1b + 262144;
    unsigned short* W3b = W2b + 262144;
    unsigned short* W4b = W3b + 65536;

    cvt_kernel<<<1600, 256, 0, stream>>>(X, Z, Y, W1, W2, W3, W4,
                                         Xb, Zb, Yb, W1b, W2b, W3b, W4b);
    gemm_mfma_kernel<<<320, 256, 0, stream>>>(Xb, Zb, Yb, W1b, W2b, W3b, W4b,
                                              b1, b2, b3, b4, H, Fo, O2, O3);
    attn_kernel<<<512, 512, 0, stream>>>(H, Fo, X, O2, O3, Y, out);
}